// Round 3
// baseline (3673.289 us; speedup 1.0000x reference)
//
#include <hip/hip_runtime.h>

#define HH 50   // hidden size
#define HP 64   // padded hidden (lanes)
#define RB 8    // batch elements per block
#define TT 512  // timesteps
#define FF 4    // input features

__device__ __forceinline__ float sigm(float x)   { return 1.0f / (1.0f + __expf(-x)); }
__device__ __forceinline__ float tanh_f(float x) { return 1.0f - 2.0f / (1.0f + __expf(2.0f * x)); }

// 8B-aligned float4 gather (weight rows are 200 B apart -> only 8 B aligned)
__device__ __forceinline__ float4 ld4u(const float* p) {
    const float2 a = *(const float2*)p;
    const float2 b = *(const float2*)(p + 2);
    return make_float4(a.x, a.y, b.x, b.y);
}

// Declare one weight row (50 floats) as named SSA values: 12 float4 + 1 float2.
// Named variables (not arrays) so no SROA/unroll pass is needed to put them in VGPRs.
#define DECLW(P, BASE) \
    const float4 P##0  = ld4u((BASE) + 0);  const float4 P##1  = ld4u((BASE) + 4);  \
    const float4 P##2  = ld4u((BASE) + 8);  const float4 P##3  = ld4u((BASE) + 12); \
    const float4 P##4  = ld4u((BASE) + 16); const float4 P##5  = ld4u((BASE) + 20); \
    const float4 P##6  = ld4u((BASE) + 24); const float4 P##7  = ld4u((BASE) + 28); \
    const float4 P##8  = ld4u((BASE) + 32); const float4 P##9  = ld4u((BASE) + 36); \
    const float4 P##10 = ld4u((BASE) + 40); const float4 P##11 = ld4u((BASE) + 44); \
    const float2 P##t  = *(const float2*)((BASE) + 48);

// layer-0 gate: one j-step = broadcast h-read (wave-uniform addr) + 8 FMA
#define L0_STEP(W, J) { \
    const float4 ha = *(const float4*)&h0buf[(J)][0]; \
    const float4 hb = *(const float4*)&h0buf[(J)][4]; \
    acc0 = fmaf((W), ha.x, acc0); acc1 = fmaf((W), ha.y, acc1); \
    acc2 = fmaf((W), ha.z, acc2); acc3 = fmaf((W), ha.w, acc3); \
    acc4 = fmaf((W), hb.x, acc4); acc5 = fmaf((W), hb.y, acc5); \
    acc6 = fmaf((W), hb.z, acc6); acc7 = fmaf((W), hb.w, acc7); }
#define L0_CHUNK(V, JB) \
    L0_STEP((V).x, (JB)) L0_STEP((V).y, (JB)+1) L0_STEP((V).z, (JB)+2) L0_STEP((V).w, (JB)+3)

// layer-1 gate: one j-step = 2 broadcast reads (h0 input + h1 recurrent) + 16 FMA
#define L1_STEP(WI, WH, J) { \
    const float4 pa = *(const float4*)&h0buf[(J)][0]; \
    const float4 pb = *(const float4*)&h0buf[(J)][4]; \
    const float4 qa = *(const float4*)&h1buf[(J)][0]; \
    const float4 qb = *(const float4*)&h1buf[(J)][4]; \
    acc0 = fmaf((WI), pa.x, fmaf((WH), qa.x, acc0)); \
    acc1 = fmaf((WI), pa.y, fmaf((WH), qa.y, acc1)); \
    acc2 = fmaf((WI), pa.z, fmaf((WH), qa.z, acc2)); \
    acc3 = fmaf((WI), pa.w, fmaf((WH), qa.w, acc3)); \
    acc4 = fmaf((WI), pb.x, fmaf((WH), qb.x, acc4)); \
    acc5 = fmaf((WI), pb.y, fmaf((WH), qb.y, acc5)); \
    acc6 = fmaf((WI), pb.z, fmaf((WH), qb.z, acc6)); \
    acc7 = fmaf((WI), pb.w, fmaf((WH), qb.w, acc7)); }
#define L1_CHUNK(VI, VH, JB) \
    L1_STEP((VI).x, (VH).x, (JB))   L1_STEP((VI).y, (VH).y, (JB)+1) \
    L1_STEP((VI).z, (VH).z, (JB)+2) L1_STEP((VI).w, (VH).w, (JB)+3)

#define STORE_G(FN) \
    gbuf[w][0][U] = FN(acc0); gbuf[w][1][U] = FN(acc1); \
    gbuf[w][2][U] = FN(acc2); gbuf[w][3][U] = FN(acc3); \
    gbuf[w][4][U] = FN(acc4); gbuf[w][5][U] = FN(acc5); \
    gbuf[w][6][U] = FN(acc6); gbuf[w][7][U] = FN(acc7);

#define XP(R, A) { const float4 xv = xbuf[tm][R]; \
    A = fmaf(w0v.x, xv.x, fmaf(w0v.y, xv.y, fmaf(w0v.z, xv.z, fmaf(w0v.w, xv.w, bias0)))); }

__attribute__((amdgpu_waves_per_eu(2, 2)))
__launch_bounds__(256)
__global__ void lstm2_kernel(const float* __restrict__ x,
                             const float* __restrict__ Wih0, const float* __restrict__ Whh0,
                             const float* __restrict__ bih0, const float* __restrict__ bhh0,
                             const float* __restrict__ Wih1, const float* __restrict__ Whh1,
                             const float* __restrict__ bih1, const float* __restrict__ bhh1,
                             const float* __restrict__ fcW,  const float* __restrict__ fcb,
                             float* __restrict__ out)
{
    __shared__ __align__(16) float h0buf[HP][RB];
    __shared__ __align__(16) float h1buf[HP][RB];
    __shared__ float gbuf[4][RB][HP];
    __shared__ __align__(16) float4 xbuf[64][RB];

    const int tid = threadIdx.x;
    const int w   = tid >> 6;   // wave id = gate type (0=i,1=f,2=g,3=o)
    const int U   = tid & 63;   // lane = hidden unit
    const int b0  = blockIdx.x * RB;
    // lanes U>=50 duplicate row 49; their LDS slots are never read
    const int row = w * HH + (U < HH ? U : HH - 1);

    for (int i = tid; i < HP * RB; i += 256) {
        (&h0buf[0][0])[i] = 0.0f;
        (&h1buf[0][0])[i] = 0.0f;
    }

    // ---- all weights as named SSA values (VGPR-resident, reused 512x) ----
    DECLW(wA, Whh0 + row * HH)   // layer0 recurrent
    DECLW(wB, Wih1 + row * HH)   // layer1 input
    DECLW(wC, Whh1 + row * HH)   // layer1 recurrent
    const float4 w0v   = ld4u(Wih0 + row * FF);
    const float  bias0 = bih0[row] + bhh0[row];
    const float  bias1 = bih1[row] + bhh1[row];

    const int r0 = 2 * w, r1 = 2 * w + 1;
    float c0a = 0.0f, c0b = 0.0f, c1a = 0.0f, c1b = 0.0f;

    __syncthreads();

    for (int t = 0; t < TT; t++) {
        if ((t & 63) == 0) {
            __syncthreads();
            #pragma unroll
            for (int it = 0; it < 2; it++) {
                const int q  = tid + it * 256;
                const int r  = q >> 6;
                const int tl = q & 63;
                xbuf[tl][r] = *(const float4*)(x + ((size_t)(b0 + r) * TT + (t + tl)) * FF);
            }
            __syncthreads();
        }
        const int tm = t & 63;

        // ---------- layer 0 gates ----------
        float acc0, acc1, acc2, acc3, acc4, acc5, acc6, acc7;
        XP(0, acc0) XP(1, acc1) XP(2, acc2) XP(3, acc3)
        XP(4, acc4) XP(5, acc5) XP(6, acc6) XP(7, acc7)
        L0_CHUNK(wA0, 0)  L0_CHUNK(wA1, 4)   L0_CHUNK(wA2, 8)   L0_CHUNK(wA3, 12)
        L0_CHUNK(wA4, 16) L0_CHUNK(wA5, 20)  L0_CHUNK(wA6, 24)  L0_CHUNK(wA7, 28)
        L0_CHUNK(wA8, 32) L0_CHUNK(wA9, 36)  L0_CHUNK(wA10, 40) L0_CHUNK(wA11, 44)
        L0_STEP(wAt.x, 48) L0_STEP(wAt.y, 49)
        if (w == 2) { STORE_G(tanh_f) } else { STORE_G(sigm) }
        __syncthreads();

        // ---------- layer 0 elementwise (this wave owns r0, r1) ----------
        {
            const float i0 = gbuf[0][r0][U], f0 = gbuf[1][r0][U], g0 = gbuf[2][r0][U], o0 = gbuf[3][r0][U];
            c0a = fmaf(f0, c0a, i0 * g0);
            h0buf[U][r0] = o0 * tanh_f(c0a);
            const float i1 = gbuf[0][r1][U], f1 = gbuf[1][r1][U], g1 = gbuf[2][r1][U], o1 = gbuf[3][r1][U];
            c0b = fmaf(f1, c0b, i1 * g1);
            h0buf[U][r1] = o1 * tanh_f(c0b);
        }
        __syncthreads();

        // ---------- layer 1 gates ----------
        acc0 = bias1; acc1 = bias1; acc2 = bias1; acc3 = bias1;
        acc4 = bias1; acc5 = bias1; acc6 = bias1; acc7 = bias1;
        L1_CHUNK(wB0, wC0, 0)   L1_CHUNK(wB1, wC1, 4)   L1_CHUNK(wB2, wC2, 8)
        L1_CHUNK(wB3, wC3, 12)  L1_CHUNK(wB4, wC4, 16)  L1_CHUNK(wB5, wC5, 20)
        L1_CHUNK(wB6, wC6, 24)  L1_CHUNK(wB7, wC7, 28)  L1_CHUNK(wB8, wC8, 32)
        L1_CHUNK(wB9, wC9, 36)  L1_CHUNK(wB10, wC10, 40) L1_CHUNK(wB11, wC11, 44)
        L1_STEP(wBt.x, wCt.x, 48) L1_STEP(wBt.y, wCt.y, 49)
        if (w == 2) { STORE_G(tanh_f) } else { STORE_G(sigm) }
        __syncthreads();

        // ---------- layer 1 elementwise ----------
        {
            const float i0 = gbuf[0][r0][U], f0 = gbuf[1][r0][U], g0 = gbuf[2][r0][U], o0 = gbuf[3][r0][U];
            c1a = fmaf(f0, c1a, i0 * g0);
            h1buf[U][r0] = o0 * tanh_f(c1a);
            const float i1 = gbuf[0][r1][U], f1 = gbuf[1][r1][U], g1 = gbuf[2][r1][U], o1 = gbuf[3][r1][U];
            c1b = fmaf(f1, c1b, i1 * g1);
            h1buf[U][r1] = o1 * tanh_f(c1b);
        }
        __syncthreads();
    }

    // ---------- final FC: out[b] = fcW @ h1_T + fcb ----------
    if (tid < 32) {
        const int r  = tid >> 2;
        const int ft = tid & 3;
        float s = fcb[ft];
        #pragma unroll
        for (int j = 0; j < HH; j++) s = fmaf(fcW[ft * HH + j], h1buf[j][r], s);
        out[(size_t)(b0 + r) * FF + ft] = s;
    }
}

extern "C" void kernel_launch(void* const* d_in, const int* in_sizes, int n_in,
                              void* d_out, int out_size, void* d_ws, size_t ws_size,
                              hipStream_t stream) {
    const float* x    = (const float*)d_in[0];
    const float* Wih0 = (const float*)d_in[1];
    const float* Whh0 = (const float*)d_in[2];
    const float* bih0 = (const float*)d_in[3];
    const float* bhh0 = (const float*)d_in[4];
    const float* Wih1 = (const float*)d_in[5];
    const float* Whh1 = (const float*)d_in[6];
    const float* bih1 = (const float*)d_in[7];
    const float* bhh1 = (const float*)d_in[8];
    const float* fcW  = (const float*)d_in[9];
    const float* fcb  = (const float*)d_in[10];
    float* out = (float*)d_out;

    const int B = in_sizes[0] / (TT * FF);   // 4096
    dim3 grid(B / RB);                        // 512 blocks, 2 per CU
    lstm2_kernel<<<grid, 256, 0, stream>>>(x, Wih0, Whh0, bih0, bhh0,
                                           Wih1, Whh1, bih1, bhh1, fcW, fcb, out);
}

// Round 4
// 3660.895 us; speedup vs baseline: 1.0034x; 1.0034x over previous
//
#include <hip/hip_runtime.h>

#define HH 50   // hidden size
#define HP 64   // padded hidden (lanes)
#define RB 8    // batch elements per block
#define TT 512  // timesteps
#define FF 4    // input features

__device__ __forceinline__ float sigm(float x)   { return 1.0f / (1.0f + __expf(-x)); }
__device__ __forceinline__ float tanh_f(float x) { return 1.0f - 2.0f / (1.0f + __expf(2.0f * x)); }

// 8B-aligned float4 gather (weight rows are 200 B apart -> only 8 B aligned)
__device__ __forceinline__ float4 ld4u(const float* p) {
    const float2 a = *(const float2*)p;
    const float2 b = *(const float2*)(p + 2);
    return make_float4(a.x, a.y, b.x, b.y);
}

// Pin a value into a VGPR as an opaque asm result: the t-loop then consumes a
// register VALUE, not a load -- the backend cannot sink the load into the loop.
#define PIN4(V) asm volatile("" : "+v"((V).x), "+v"((V).y), "+v"((V).z), "+v"((V).w));
#define PIN2(V) asm volatile("" : "+v"((V).x), "+v"((V).y));
#define PIN1(S) asm volatile("" : "+v"(S));

// Declare one weight row (50 floats) as named values: 12 float4 + 1 float2.
#define DECLW(P, BASE) \
    float4 P##0  = ld4u((BASE) + 0);  float4 P##1  = ld4u((BASE) + 4);  \
    float4 P##2  = ld4u((BASE) + 8);  float4 P##3  = ld4u((BASE) + 12); \
    float4 P##4  = ld4u((BASE) + 16); float4 P##5  = ld4u((BASE) + 20); \
    float4 P##6  = ld4u((BASE) + 24); float4 P##7  = ld4u((BASE) + 28); \
    float4 P##8  = ld4u((BASE) + 32); float4 P##9  = ld4u((BASE) + 36); \
    float4 P##10 = ld4u((BASE) + 40); float4 P##11 = ld4u((BASE) + 44); \
    float2 P##t  = *(const float2*)((BASE) + 48);

#define PINW(P) \
    PIN4(P##0)  PIN4(P##1)  PIN4(P##2)  PIN4(P##3)  PIN4(P##4)  PIN4(P##5) \
    PIN4(P##6)  PIN4(P##7)  PIN4(P##8)  PIN4(P##9)  PIN4(P##10) PIN4(P##11) \
    PIN2(P##t)

// layer-0 gate: one j-step = broadcast h-read (wave-uniform addr) + 8 FMA
#define L0_STEP(W, J) { \
    const float4 ha = *(const float4*)&h0buf[(J)][0]; \
    const float4 hb = *(const float4*)&h0buf[(J)][4]; \
    acc0 = fmaf((W), ha.x, acc0); acc1 = fmaf((W), ha.y, acc1); \
    acc2 = fmaf((W), ha.z, acc2); acc3 = fmaf((W), ha.w, acc3); \
    acc4 = fmaf((W), hb.x, acc4); acc5 = fmaf((W), hb.y, acc5); \
    acc6 = fmaf((W), hb.z, acc6); acc7 = fmaf((W), hb.w, acc7); }
#define L0_CHUNK(V, JB) \
    L0_STEP((V).x, (JB)) L0_STEP((V).y, (JB)+1) L0_STEP((V).z, (JB)+2) L0_STEP((V).w, (JB)+3)

// layer-1 gate: one j-step = 2 broadcast reads (h0 input + h1 recurrent) + 16 FMA
#define L1_STEP(WI, WH, J) { \
    const float4 pa = *(const float4*)&h0buf[(J)][0]; \
    const float4 pb = *(const float4*)&h0buf[(J)][4]; \
    const float4 qa = *(const float4*)&h1buf[(J)][0]; \
    const float4 qb = *(const float4*)&h1buf[(J)][4]; \
    acc0 = fmaf((WI), pa.x, fmaf((WH), qa.x, acc0)); \
    acc1 = fmaf((WI), pa.y, fmaf((WH), qa.y, acc1)); \
    acc2 = fmaf((WI), pa.z, fmaf((WH), qa.z, acc2)); \
    acc3 = fmaf((WI), pa.w, fmaf((WH), qa.w, acc3)); \
    acc4 = fmaf((WI), pb.x, fmaf((WH), qb.x, acc4)); \
    acc5 = fmaf((WI), pb.y, fmaf((WH), qb.y, acc5)); \
    acc6 = fmaf((WI), pb.z, fmaf((WH), qb.z, acc6)); \
    acc7 = fmaf((WI), pb.w, fmaf((WH), qb.w, acc7)); }
#define L1_CHUNK(VI, VH, JB) \
    L1_STEP((VI).x, (VH).x, (JB))   L1_STEP((VI).y, (VH).y, (JB)+1) \
    L1_STEP((VI).z, (VH).z, (JB)+2) L1_STEP((VI).w, (VH).w, (JB)+3)

#define STORE_G(FN) \
    gbuf[w][0][U] = FN(acc0); gbuf[w][1][U] = FN(acc1); \
    gbuf[w][2][U] = FN(acc2); gbuf[w][3][U] = FN(acc3); \
    gbuf[w][4][U] = FN(acc4); gbuf[w][5][U] = FN(acc5); \
    gbuf[w][6][U] = FN(acc6); gbuf[w][7][U] = FN(acc7);

#define XP(R, A) { const float4 xv = xbuf[tm][R]; \
    A = fmaf(w0v.x, xv.x, fmaf(w0v.y, xv.y, fmaf(w0v.z, xv.z, fmaf(w0v.w, xv.w, bias0)))); }

__attribute__((amdgpu_waves_per_eu(2, 2)))
__launch_bounds__(256)
__global__ void lstm2_kernel(const float* __restrict__ x,
                             const float* __restrict__ Wih0, const float* __restrict__ Whh0,
                             const float* __restrict__ bih0, const float* __restrict__ bhh0,
                             const float* __restrict__ Wih1, const float* __restrict__ Whh1,
                             const float* __restrict__ bih1, const float* __restrict__ bhh1,
                             const float* __restrict__ fcW,  const float* __restrict__ fcb,
                             float* __restrict__ out)
{
    __shared__ __align__(16) float h0buf[HP][RB];
    __shared__ __align__(16) float h1buf[HP][RB];
    __shared__ float gbuf[4][RB][HP];
    __shared__ __align__(16) float4 xbuf[64][RB];

    const int tid = threadIdx.x;
    const int w   = tid >> 6;   // wave id = gate type (0=i,1=f,2=g,3=o)
    const int U   = tid & 63;   // lane = hidden unit
    const int b0  = blockIdx.x * RB;
    // lanes U>=50 duplicate row 49; their LDS slots are never read
    const int row = w * HH + (U < HH ? U : HH - 1);

    for (int i = tid; i < HP * RB; i += 256) {
        (&h0buf[0][0])[i] = 0.0f;
        (&h1buf[0][0])[i] = 0.0f;
    }

    // ---- all weights loaded once, then pinned as opaque VGPR values ----
    DECLW(wA, Whh0 + row * HH)   // layer0 recurrent
    DECLW(wB, Wih1 + row * HH)   // layer1 input
    DECLW(wC, Whh1 + row * HH)   // layer1 recurrent
    float4 w0v   = ld4u(Wih0 + row * FF);
    float  bias0 = bih0[row] + bhh0[row];
    float  bias1 = bih1[row] + bhh1[row];
    PINW(wA) PINW(wB) PINW(wC)
    PIN4(w0v) PIN1(bias0) PIN1(bias1)

    const int r0 = 2 * w, r1 = 2 * w + 1;
    float c0a = 0.0f, c0b = 0.0f, c1a = 0.0f, c1b = 0.0f;

    __syncthreads();

    for (int t = 0; t < TT; t++) {
        if ((t & 63) == 0) {
            __syncthreads();
            #pragma unroll
            for (int it = 0; it < 2; it++) {
                const int q  = tid + it * 256;
                const int r  = q >> 6;
                const int tl = q & 63;
                xbuf[tl][r] = *(const float4*)(x + ((size_t)(b0 + r) * TT + (t + tl)) * FF);
            }
            __syncthreads();
        }
        const int tm = t & 63;

        // ---------- layer 0 gates ----------
        float acc0, acc1, acc2, acc3, acc4, acc5, acc6, acc7;
        XP(0, acc0) XP(1, acc1) XP(2, acc2) XP(3, acc3)
        XP(4, acc4) XP(5, acc5) XP(6, acc6) XP(7, acc7)
        L0_CHUNK(wA0, 0)  L0_CHUNK(wA1, 4)   L0_CHUNK(wA2, 8)   L0_CHUNK(wA3, 12)
        L0_CHUNK(wA4, 16) L0_CHUNK(wA5, 20)  L0_CHUNK(wA6, 24)  L0_CHUNK(wA7, 28)
        L0_CHUNK(wA8, 32) L0_CHUNK(wA9, 36)  L0_CHUNK(wA10, 40) L0_CHUNK(wA11, 44)
        L0_STEP(wAt.x, 48) L0_STEP(wAt.y, 49)
        if (w == 2) { STORE_G(tanh_f) } else { STORE_G(sigm) }
        __syncthreads();

        // ---------- layer 0 elementwise (this wave owns r0, r1) ----------
        {
            const float i0 = gbuf[0][r0][U], f0 = gbuf[1][r0][U], g0 = gbuf[2][r0][U], o0 = gbuf[3][r0][U];
            c0a = fmaf(f0, c0a, i0 * g0);
            h0buf[U][r0] = o0 * tanh_f(c0a);
            const float i1 = gbuf[0][r1][U], f1 = gbuf[1][r1][U], g1 = gbuf[2][r1][U], o1 = gbuf[3][r1][U];
            c0b = fmaf(f1, c0b, i1 * g1);
            h0buf[U][r1] = o1 * tanh_f(c0b);
        }
        __syncthreads();

        // ---------- layer 1 gates ----------
        acc0 = bias1; acc1 = bias1; acc2 = bias1; acc3 = bias1;
        acc4 = bias1; acc5 = bias1; acc6 = bias1; acc7 = bias1;
        L1_CHUNK(wB0, wC0, 0)   L1_CHUNK(wB1, wC1, 4)   L1_CHUNK(wB2, wC2, 8)
        L1_CHUNK(wB3, wC3, 12)  L1_CHUNK(wB4, wC4, 16)  L1_CHUNK(wB5, wC5, 20)
        L1_CHUNK(wB6, wC6, 24)  L1_CHUNK(wB7, wC7, 28)  L1_CHUNK(wB8, wC8, 32)
        L1_CHUNK(wB9, wC9, 36)  L1_CHUNK(wB10, wC10, 40) L1_CHUNK(wB11, wC11, 44)
        L1_STEP(wBt.x, wCt.x, 48) L1_STEP(wBt.y, wCt.y, 49)
        if (w == 2) { STORE_G(tanh_f) } else { STORE_G(sigm) }
        __syncthreads();

        // ---------- layer 1 elementwise ----------
        {
            const float i0 = gbuf[0][r0][U], f0 = gbuf[1][r0][U], g0 = gbuf[2][r0][U], o0 = gbuf[3][r0][U];
            c1a = fmaf(f0, c1a, i0 * g0);
            h1buf[U][r0] = o0 * tanh_f(c1a);
            const float i1 = gbuf[0][r1][U], f1 = gbuf[1][r1][U], g1 = gbuf[2][r1][U], o1 = gbuf[3][r1][U];
            c1b = fmaf(f1, c1b, i1 * g1);
            h1buf[U][r1] = o1 * tanh_f(c1b);
        }
        __syncthreads();
    }

    // ---------- final FC: out[b] = fcW @ h1_T + fcb ----------
    if (tid < 32) {
        const int r  = tid >> 2;
        const int ft = tid & 3;
        float s = fcb[ft];
        #pragma unroll
        for (int j = 0; j < HH; j++) s = fmaf(fcW[ft * HH + j], h1buf[j][r], s);
        out[(size_t)(b0 + r) * FF + ft] = s;
    }
}

extern "C" void kernel_launch(void* const* d_in, const int* in_sizes, int n_in,
                              void* d_out, int out_size, void* d_ws, size_t ws_size,
                              hipStream_t stream) {
    const float* x    = (const float*)d_in[0];
    const float* Wih0 = (const float*)d_in[1];
    const float* Whh0 = (const float*)d_in[2];
    const float* bih0 = (const float*)d_in[3];
    const float* bhh0 = (const float*)d_in[4];
    const float* Wih1 = (const float*)d_in[5];
    const float* Whh1 = (const float*)d_in[6];
    const float* bih1 = (const float*)d_in[7];
    const float* bhh1 = (const float*)d_in[8];
    const float* fcW  = (const float*)d_in[9];
    const float* fcb  = (const float*)d_in[10];
    float* out = (float*)d_out;

    const int B = in_sizes[0] / (TT * FF);   // 4096
    dim3 grid(B / RB);                        // 512 blocks, 2 per CU
    lstm2_kernel<<<grid, 256, 0, stream>>>(x, Wih0, Whh0, bih0, bhh0,
                                           Wih1, Whh1, bih1, bhh1, fcW, fcb, out);
}